// Round 3
// baseline (1472.718 us; speedup 1.0000x reference)
//
#include <hip/hip_runtime.h>

#define T_LEN 131072
#define KDIM 128
#define CHUNK 32
#define WARM 16
#define NCHUNK 4096   // ceil(131071/32)

typedef float v2f __attribute__((ext_vector_type(2)));

__device__ __forceinline__ void decode4(unsigned int pk, float& e0, float& e1, float& e2, float& e3) {
    v2f lo = __builtin_amdgcn_cvt_pk_f32_fp8((int)pk, false);
    v2f hi = __builtin_amdgcn_cvt_pk_f32_fp8((int)pk, true);
    e0 = lo.x; e1 = lo.y; e2 = hi.x; e3 = hi.y;
}

__device__ __forceinline__ int trans_idx(int w2w, int ic, int dist) {
    return (w2w == 1) ? 0 : (ic == 0 ? 1 : (dist == 0 ? 2 : 3));
}

// ---- prep (fused): idxArr + swizzled fp8 E ----
// Eswz dword index = (m<<12) | (h<<9) | (p<<4) | k  holds fp8x4 of
// exp(trans[m][16h+k][4p+j]), j=0..3. A lane (h,p) reads its 16 step-dwords
// contiguously -> 4x global_load_dwordx4.
__global__ void prep_kernel(const float* __restrict__ trans,
                            const int* __restrict__ w2w, const int* __restrict__ ic,
                            const int* __restrict__ dist,
                            unsigned int* __restrict__ Eswz, unsigned char* __restrict__ idxArr) {
    int tid = blockIdx.x * blockDim.x + threadIdx.x;
    if (tid < T_LEN - 1) idxArr[tid] = (unsigned char)trans_idx(w2w[tid], ic[tid], dist[tid]);
    if (tid < 16384) {
        const int m = tid >> 12, r = tid & 4095;
        const int h = r >> 9, p = (r >> 4) & 31, k = r & 15;
        const int i = (h << 4) + k;
        const float* src = trans + ((size_t)m << 14) + (i << 7) + (p << 2);
        unsigned int out = 0;
        #pragma unroll
        for (int j = 0; j < 4; ++j) {
            float e = __expf(src[j]);
            unsigned int u = __float_as_uint(e) - 0x3C000000u;      // rebias to e4m3 at bit20
            unsigned int b = (u + 0x7FFFFu + ((u >> 20) & 1u)) >> 20; // RNE
            out |= (b & 0xffu) << (8 * j);
        }
        Eswz[tid] = out;
    }
}

// ---- gold: parallel gather + reduce ----
__global__ void gold_kernel(const float* __restrict__ em, const float* __restrict__ trans,
                            const float* __restrict__ start, const float* __restrict__ cw,
                            const int* __restrict__ tags, const int* __restrict__ w2w,
                            const int* __restrict__ ic, const int* __restrict__ dist,
                            double* __restrict__ gold_acc) {
    int tid = blockIdx.x * blockDim.x + threadIdx.x;
    int stride = gridDim.x * blockDim.x;
    float part = 0.f;
    for (int t = tid; t < T_LEN; t += stride) {
        int tg = tags[t];
        float wt = cw[tg];
        float emv = em[(size_t)t * KDIM + tg];
        if (t == 0) {
            part += wt * (start[tg] + emv);
        } else {
            int m = trans_idx(w2w[t - 1], ic[t - 1], dist[t - 1]);
            int tgp = tags[t - 1];
            part += wt * (trans[((size_t)m * KDIM + tgp) * KDIM + tg] + emv);
        }
    }
    __shared__ float red[256];
    red[threadIdx.x] = part;
    __syncthreads();
    for (int s = 128; s > 0; s >>= 1) {
        if (threadIdx.x < (unsigned)s) red[threadIdx.x] += red[threadIdx.x + s];
        __syncthreads();
    }
    if (threadIdx.x == 0) atomicAdd(gold_acc, (double)red[0]);
}

// ---- scan: one chunk per block, register-prefetched swizzled fp8 E ----
__global__ void __launch_bounds__(256, 8) scan_kernel(
    const float* __restrict__ em, const unsigned char* __restrict__ Eswz,
    const unsigned char* __restrict__ idxArr, const float* __restrict__ start,
    double* __restrict__ logz_acc)
{
    const int c   = blockIdx.x;
    const int tau = threadIdx.x;
    const int p   = tau & 31;   // column group: cols 4p..4p+3
    const int h   = tau >> 5;   // i-group: i in [16h, 16h+16)

    __shared__ float v_lds[KDIM];
    __shared__ __align__(16) float partial[8][KDIM];
    __shared__ float wsum[2];

    const int t_own = 1 + c * CHUNK;
    const int t_end = min(t_own + CHUNK, T_LEN);
    const int t0    = (c == 0) ? 1 : (t_own - WARM);

    // lane's 64B base within a matrix (dword index (h<<9)|(p<<4))
    const size_t lane_off = ((size_t)((h << 5) + p)) << 6;

    // ---- init v ----
    float myv = 0.f;
    if (tau < KDIM) {
        myv = (c == 0) ? __expf(start[tau] + em[tau]) : 1.0f;
        v_lds[tau] = myv;
    }
    float r0 = myv;
    #pragma unroll
    for (int off = 32; off; off >>= 1) r0 += __shfl_down(r0, off, 64);
    if (tau < KDIM && (tau & 63) == 0) wsum[tau >> 6] = r0;
    __syncthreads();
    const float s0 = wsum[0] + wsum[1];
    float scale = 1.0f / s0;

    float g = 0.f;
    if (c == 0 && tau == 0) g = __logf(s0);

    // ---- software pipeline priming ----
    // cur = E regs for step t0; m1 = matrix for step t0+1
    int m_cur = idxArr[t0 - 1];
    const uint4* csrc = (const uint4*)(Eswz + (((size_t)m_cur) << 14) + lane_off);
    uint4 cur0 = csrc[0], cur1 = csrc[1], cur2 = csrc[2], cur3 = csrc[3];
    int m1 = idxArr[min(t0, T_LEN - 2)];
    float em_pref = (tau < KDIM) ? em[(size_t)t0 * KDIM + tau] : 0.f;

    for (int t = t0; t < t_end; ++t) {
        const float d = __expf(em_pref);

        // issue next step's E loads NOW (consumed after barrier next iter)
        const uint4* nsrc = (const uint4*)(Eswz + (((size_t)m1) << 14) + lane_off);
        uint4 n0 = nsrc[0], n1 = nsrc[1], n2 = nsrc[2], n3 = nsrc[3];
        const int tn = (t + 1 < t_end) ? (t + 1) : t;
        m1 = idxArr[min(tn, T_LEN - 2)];                  // matrix for step tn+1
        if (tau < KDIM) em_pref = em[(size_t)tn * KDIM + tau];

        // phase 1: partial matvec with current regs. cols 4p..4p+3, i in [16h,16h+16)
        float a0 = 0.f, a1 = 0.f, a2 = 0.f, a3 = 0.f;
        const int ib = h << 4;
        const unsigned int pk[16] = {cur0.x, cur0.y, cur0.z, cur0.w,
                                     cur1.x, cur1.y, cur1.z, cur1.w,
                                     cur2.x, cur2.y, cur2.z, cur2.w,
                                     cur3.x, cur3.y, cur3.z, cur3.w};
        #pragma unroll
        for (int k = 0; k < 16; ++k) {
            const float vi = v_lds[ib + k];
            float e0, e1, e2, e3;
            decode4(pk[k], e0, e1, e2, e3);
            a0 = fmaf(vi, e0, a0);
            a1 = fmaf(vi, e1, a1);
            a2 = fmaf(vi, e2, a2);
            a3 = fmaf(vi, e3, a3);
        }
        *reinterpret_cast<float4*>(&partial[h][p << 2]) = make_float4(a0, a1, a2, a3);
        __syncthreads();

        // phase 2: combine 8 partials, apply emission + pending scale
        const bool donorm = ((t & 3) == 0) || (t == T_LEN - 1);
        float tot = 0.f;
        if (tau < KDIM) {
            tot = (partial[0][tau] + partial[1][tau] + partial[2][tau] + partial[3][tau] +
                   partial[4][tau] + partial[5][tau] + partial[6][tau] + partial[7][tau]) * (d * scale);
            v_lds[tau] = tot;
        }
        if (donorm) {
            float r = tot;
            #pragma unroll
            for (int off = 32; off; off >>= 1) r += __shfl_down(r, off, 64);
            if (tau < KDIM && (tau & 63) == 0) wsum[tau >> 6] = r;
        }
        __syncthreads();
        if (donorm) {
            const float s = wsum[0] + wsum[1];
            scale = 1.0f / s;
            if (tau == 0 && t >= t_own) g += __logf(s);
        } else {
            scale = 1.0f;
        }

        cur0 = n0; cur1 = n1; cur2 = n2; cur3 = n3;
    }

    if (tau == 0) atomicAdd(logz_acc, (double)g);
}

__global__ void finalize_kernel(const double* __restrict__ acc, float* __restrict__ out) {
    if (threadIdx.x == 0 && blockIdx.x == 0) {
        out[0] = (float)acc[0];
        out[1] = (float)acc[1];
    }
}

extern "C" void kernel_launch(void* const* d_in, const int* in_sizes, int n_in,
                              void* d_out, int out_size, void* d_ws, size_t ws_size,
                              hipStream_t stream) {
    const float* emissions = (const float*)d_in[0];
    const float* trans     = (const float*)d_in[1];
    const float* start     = (const float*)d_in[2];
    const float* cw        = (const float*)d_in[3];
    const int*   tags      = (const int*)d_in[4];
    const int*   w2w       = (const int*)d_in[5];
    const int*   icnt      = (const int*)d_in[6];
    const int*   dist      = (const int*)d_in[7];

    double*        accs   = (double*)d_ws;                         // [0]=gold, [1]=logz
    unsigned char* Eswz   = (unsigned char*)d_ws + 64;             // 65536 B swizzled fp8
    unsigned char* idxArr = (unsigned char*)d_ws + 64 + 65536;     // T-1 bytes

    hipMemsetAsync(d_ws, 0, 16, stream);
    prep_kernel<<<512, 256, 0, stream>>>(trans, w2w, icnt, dist, (unsigned int*)Eswz, idxArr);
    gold_kernel<<<512, 256, 0, stream>>>(emissions, trans, start, cw, tags, w2w, icnt, dist, &accs[0]);
    scan_kernel<<<NCHUNK, 256, 0, stream>>>(emissions, Eswz, idxArr, start, &accs[1]);
    finalize_kernel<<<1, 64, 0, stream>>>(accs, (float*)d_out);
}

// Round 4
// 291.069 us; speedup vs baseline: 5.0597x; 5.0597x over previous
//
#include <hip/hip_runtime.h>

#define T_LEN 131072
#define KDIM 128
#define CHUNK 128
#define WARM 16
#define NCHUNK 1024   // ceil(131071/128)

typedef float v2f __attribute__((ext_vector_type(2)));

__device__ __forceinline__ void decode4(unsigned int pk, float& e0, float& e1, float& e2, float& e3) {
    v2f lo = __builtin_amdgcn_cvt_pk_f32_fp8((int)pk, false);
    v2f hi = __builtin_amdgcn_cvt_pk_f32_fp8((int)pk, true);
    e0 = lo.x; e1 = lo.y; e2 = hi.x; e3 = hi.y;
}

__device__ __forceinline__ int trans_idx(int w2w, int ic, int dist) {
    return (w2w == 1) ? 0 : (ic == 0 ? 1 : (dist == 0 ? 2 : 3));
}

// ---- prep: idxArr + swizzled fp8 E in the LDS-friendly layout ----
// Eswz dword idx = m*4096 + j4*1024 + L*4 + e, where thread L=(h,p) (h=L>>5,
// p=L&31) owns rows i=16h+k (k=j4*4+e) and cols 4p..4p+3; the dword packs
// fp8(exp(trans[m][i][4p+j])) in byte j.
__global__ void prep_kernel(const float* __restrict__ trans,
                            const int* __restrict__ w2w, const int* __restrict__ ic,
                            const int* __restrict__ dist,
                            unsigned int* __restrict__ Eswz, unsigned char* __restrict__ idxArr) {
    int tid = blockIdx.x * blockDim.x + threadIdx.x;
    if (tid < T_LEN - 1) idxArr[tid] = (unsigned char)trans_idx(w2w[tid], ic[tid], dist[tid]);
    if (tid < 16384) {
        const int m = tid >> 12, r = tid & 4095;
        const int j4 = r >> 10, L = (r >> 2) & 255, e = r & 3;
        const int k = (j4 << 2) | e;
        const int i = ((L >> 5) << 4) + k;
        const float* src = trans + ((size_t)m << 14) + (i << 7) + ((L & 31) << 2);
        unsigned int out = 0;
        #pragma unroll
        for (int j = 0; j < 4; ++j) {
            float ev = __expf(src[j]);
            unsigned int u = __float_as_uint(ev) - 0x3C000000u;        // rebias to e4m3 at bit20
            unsigned int b = (u + 0x7FFFFu + ((u >> 20) & 1u)) >> 20;  // RNE
            out |= (b & 0xffu) << (8 * j);
        }
        Eswz[tid] = out;
    }
}

// ---- gold: parallel gather + reduce ----
__global__ void gold_kernel(const float* __restrict__ em, const float* __restrict__ trans,
                            const float* __restrict__ start, const float* __restrict__ cw,
                            const int* __restrict__ tags, const int* __restrict__ w2w,
                            const int* __restrict__ ic, const int* __restrict__ dist,
                            double* __restrict__ gold_acc) {
    int tid = blockIdx.x * blockDim.x + threadIdx.x;
    int stride = gridDim.x * blockDim.x;
    float part = 0.f;
    for (int t = tid; t < T_LEN; t += stride) {
        int tg = tags[t];
        float wt = cw[tg];
        float emv = em[(size_t)t * KDIM + tg];
        if (t == 0) {
            part += wt * (start[tg] + emv);
        } else {
            int m = trans_idx(w2w[t - 1], ic[t - 1], dist[t - 1]);
            int tgp = tags[t - 1];
            part += wt * (trans[((size_t)m * KDIM + tgp) * KDIM + tg] + emv);
        }
    }
    __shared__ float red[256];
    red[threadIdx.x] = part;
    __syncthreads();
    for (int s = 128; s > 0; s >>= 1) {
        if (threadIdx.x < (unsigned)s) red[threadIdx.x] += red[threadIdx.x + s];
        __syncthreads();
    }
    if (threadIdx.x == 0) atomicAdd(gold_acc, (double)red[0]);
}

// ---- scan: one chunk per block; ALL 4 fp8 matrices resident in LDS ----
__global__ void __launch_bounds__(256, 2) scan_kernel(
    const float* __restrict__ em, const unsigned int* __restrict__ Eswz,
    const unsigned char* __restrict__ idxArr, const float* __restrict__ start,
    double* __restrict__ logz_acc)
{
    const int c   = blockIdx.x;
    const int tau = threadIdx.x;
    const int p   = tau & 31;   // column group: cols 4p..4p+3
    const int h   = tau >> 5;   // i-group: i in [16h, 16h+16)

    __shared__ unsigned int EL[16384];            // 64 KB: [m][j4][L][e]
    __shared__ float v_lds[KDIM];
    __shared__ __align__(16) float partial[8][KDIM];
    __shared__ float wsum[2];

    // ---- stage all 4 matrices into LDS (once) ----
    #pragma unroll
    for (int m = 0; m < 4; ++m) {
        #pragma unroll
        for (int j4 = 0; j4 < 4; ++j4) {
            const int di = (m << 12) + (j4 << 10) + (tau << 2);
            *reinterpret_cast<uint4*>(&EL[di]) = *reinterpret_cast<const uint4*>(&Eswz[di]);
        }
    }

    const int t_own = 1 + c * CHUNK;
    const int t_end = min(t_own + CHUNK, T_LEN);
    const int t0    = (c == 0) ? 1 : (t_own - WARM);

    // ---- init v ----
    float myv = 0.f;
    if (tau < KDIM) {
        myv = (c == 0) ? __expf(start[tau] + em[tau]) : 1.0f;
        v_lds[tau] = myv;
    }
    float r0 = myv;
    #pragma unroll
    for (int off = 32; off; off >>= 1) r0 += __shfl_down(r0, off, 64);
    if (tau < KDIM && (tau & 63) == 0) wsum[tau >> 6] = r0;
    __syncthreads();
    const float s0 = wsum[0] + wsum[1];
    float scale = 1.0f / s0;

    float g = 0.f;
    if (c == 0 && tau == 0) g = __logf(s0);

    // ---- scalar/emission prefetch for step t0 ----
    int   pm = idxArr[t0 - 1];
    float em_pref = (tau < KDIM) ? em[(size_t)t0 * KDIM + tau] : 0.f;

    const int ib = h << 4;

    for (int t = t0; t < t_end; ++t) {
        const int m = pm;
        const float d = __expf(em_pref);

        // prefetch next step's scalars + emission row
        const int tn = (t + 1 < t_end) ? (t + 1) : t;
        pm = idxArr[tn - 1];
        if (tau < KDIM) em_pref = em[(size_t)tn * KDIM + tau];

        // phase 1: partial matvec from LDS-resident E
        const unsigned int* Em = EL + (m << 12) + (tau << 2);
        float a0 = 0.f, a1 = 0.f, a2 = 0.f, a3 = 0.f;
        #pragma unroll
        for (int j4 = 0; j4 < 4; ++j4) {
            const uint4  pk4 = *reinterpret_cast<const uint4*>(Em + (j4 << 10));
            const float4 v4  = *reinterpret_cast<const float4*>(&v_lds[ib + (j4 << 2)]);
            float e0, e1, e2, e3;
            decode4(pk4.x, e0, e1, e2, e3);
            a0 = fmaf(v4.x, e0, a0); a1 = fmaf(v4.x, e1, a1); a2 = fmaf(v4.x, e2, a2); a3 = fmaf(v4.x, e3, a3);
            decode4(pk4.y, e0, e1, e2, e3);
            a0 = fmaf(v4.y, e0, a0); a1 = fmaf(v4.y, e1, a1); a2 = fmaf(v4.y, e2, a2); a3 = fmaf(v4.y, e3, a3);
            decode4(pk4.z, e0, e1, e2, e3);
            a0 = fmaf(v4.z, e0, a0); a1 = fmaf(v4.z, e1, a1); a2 = fmaf(v4.z, e2, a2); a3 = fmaf(v4.z, e3, a3);
            decode4(pk4.w, e0, e1, e2, e3);
            a0 = fmaf(v4.w, e0, a0); a1 = fmaf(v4.w, e1, a1); a2 = fmaf(v4.w, e2, a2); a3 = fmaf(v4.w, e3, a3);
        }
        *reinterpret_cast<float4*>(&partial[h][p << 2]) = make_float4(a0, a1, a2, a3);
        __syncthreads();

        // phase 2: combine 8 partials, apply emission + pending scale
        const bool donorm = ((t & 7) == 0) || (t == T_LEN - 1);
        float tot = 0.f;
        if (tau < KDIM) {
            tot = (partial[0][tau] + partial[1][tau] + partial[2][tau] + partial[3][tau] +
                   partial[4][tau] + partial[5][tau] + partial[6][tau] + partial[7][tau]) * (d * scale);
            v_lds[tau] = tot;
        }
        if (donorm) {
            float r = tot;
            #pragma unroll
            for (int off = 32; off; off >>= 1) r += __shfl_down(r, off, 64);
            if (tau < KDIM && (tau & 63) == 0) wsum[tau >> 6] = r;
        }
        __syncthreads();
        if (donorm) {
            const float s = wsum[0] + wsum[1];
            scale = 1.0f / s;
            if (tau == 0 && t >= t_own) g += __logf(s);
        } else {
            scale = 1.0f;
        }
    }

    if (tau == 0) atomicAdd(logz_acc, (double)g);
}

__global__ void finalize_kernel(const double* __restrict__ acc, float* __restrict__ out) {
    if (threadIdx.x == 0 && blockIdx.x == 0) {
        out[0] = (float)acc[0];
        out[1] = (float)acc[1];
    }
}

extern "C" void kernel_launch(void* const* d_in, const int* in_sizes, int n_in,
                              void* d_out, int out_size, void* d_ws, size_t ws_size,
                              hipStream_t stream) {
    const float* emissions = (const float*)d_in[0];
    const float* trans     = (const float*)d_in[1];
    const float* start     = (const float*)d_in[2];
    const float* cw        = (const float*)d_in[3];
    const int*   tags      = (const int*)d_in[4];
    const int*   w2w       = (const int*)d_in[5];
    const int*   icnt      = (const int*)d_in[6];
    const int*   dist      = (const int*)d_in[7];

    double*        accs   = (double*)d_ws;                         // [0]=gold, [1]=logz
    unsigned int*  Eswz   = (unsigned int*)((char*)d_ws + 64);     // 65536 B swizzled fp8
    unsigned char* idxArr = (unsigned char*)d_ws + 64 + 65536;     // T-1 bytes

    hipMemsetAsync(d_ws, 0, 16, stream);
    prep_kernel<<<512, 256, 0, stream>>>(trans, w2w, icnt, dist, Eswz, idxArr);
    gold_kernel<<<512, 256, 0, stream>>>(emissions, trans, start, cw, tags, w2w, icnt, dist, &accs[0]);
    scan_kernel<<<NCHUNK, 256, 0, stream>>>(emissions, Eswz, idxArr, start, &accs[1]);
    finalize_kernel<<<1, 64, 0, stream>>>(accs, (float*)d_out);
}

// Round 5
// 246.536 us; speedup vs baseline: 5.9736x; 1.1806x over previous
//
#include <hip/hip_runtime.h>

#define T_LEN 131072
#define KDIM 128
#define CHUNK 128
#define WARM 16
#define NSTEP (CHUNK + WARM)
#define NCHUNK 1024   // ceil(131071/128)

typedef float v2f __attribute__((ext_vector_type(2)));

__device__ __forceinline__ void decode4(unsigned int pk, float& e0, float& e1, float& e2, float& e3) {
    v2f lo = __builtin_amdgcn_cvt_pk_f32_fp8((int)pk, false);
    v2f hi = __builtin_amdgcn_cvt_pk_f32_fp8((int)pk, true);
    e0 = lo.x; e1 = lo.y; e2 = hi.x; e3 = hi.y;
}

__device__ __forceinline__ int trans_idx(int w2w, int ic, int dist) {
    return (w2w == 1) ? 0 : (ic == 0 ? 1 : (dist == 0 ? 2 : 3));
}

// ---- prep: idxArr + swizzled fp8 E (LDS-friendly layout, same as round 4) ----
// Eswz dword idx = m*4096 + j4*1024 + L*4 + e; thread L=(h,p) owns rows
// i=16h+k (k=j4*4+e), cols 4p..4p+3; dword packs fp8(exp(tr[m][i][4p+j])).
__global__ void prep_kernel(const float* __restrict__ trans,
                            const int* __restrict__ w2w, const int* __restrict__ ic,
                            const int* __restrict__ dist,
                            unsigned int* __restrict__ Eswz, unsigned char* __restrict__ idxArr) {
    int tid = blockIdx.x * blockDim.x + threadIdx.x;
    if (tid < T_LEN - 1) idxArr[tid] = (unsigned char)trans_idx(w2w[tid], ic[tid], dist[tid]);
    if (tid < 16384) {
        const int m = tid >> 12, r = tid & 4095;
        const int j4 = r >> 10, L = (r >> 2) & 255, e = r & 3;
        const int k = (j4 << 2) | e;
        const int i = ((L >> 5) << 4) + k;
        const float* src = trans + ((size_t)m << 14) + (i << 7) + ((L & 31) << 2);
        unsigned int out = 0;
        #pragma unroll
        for (int j = 0; j < 4; ++j) {
            float ev = __expf(src[j]);
            unsigned int u = __float_as_uint(ev) - 0x3C000000u;        // rebias to e4m3 at bit20
            unsigned int b = (u + 0x7FFFFu + ((u >> 20) & 1u)) >> 20;  // RNE
            out |= (b & 0xffu) << (8 * j);
        }
        Eswz[tid] = out;
    }
}

// ---- gold: parallel gather + reduce ----
__global__ void gold_kernel(const float* __restrict__ em, const float* __restrict__ trans,
                            const float* __restrict__ start, const float* __restrict__ cw,
                            const int* __restrict__ tags, const int* __restrict__ w2w,
                            const int* __restrict__ ic, const int* __restrict__ dist,
                            double* __restrict__ gold_acc) {
    int tid = blockIdx.x * blockDim.x + threadIdx.x;
    int stride = gridDim.x * blockDim.x;
    float part = 0.f;
    for (int t = tid; t < T_LEN; t += stride) {
        int tg = tags[t];
        float wt = cw[tg];
        float emv = em[(size_t)t * KDIM + tg];
        if (t == 0) {
            part += wt * (start[tg] + emv);
        } else {
            int m = trans_idx(w2w[t - 1], ic[t - 1], dist[t - 1]);
            int tgp = tags[t - 1];
            part += wt * (trans[((size_t)m * KDIM + tgp) * KDIM + tg] + emv);
        }
    }
    __shared__ float red[256];
    red[threadIdx.x] = part;
    __syncthreads();
    for (int s = 128; s > 0; s >>= 1) {
        if (threadIdx.x < (unsigned)s) red[threadIdx.x] += red[threadIdx.x + s];
        __syncthreads();
    }
    if (threadIdx.x == 0) atomicAdd(gold_acc, (double)red[0]);
}

// ---- scan: 512 threads = 2 chunk-pipelines sharing one LDS copy of all 4 E ----
__global__ void __launch_bounds__(512, 4) scan_kernel(
    const float* __restrict__ em, const unsigned int* __restrict__ Eswz,
    const unsigned char* __restrict__ idxArr, const float* __restrict__ start,
    double* __restrict__ logz_acc)
{
    const int pipe = threadIdx.x >> 8;      // 0 or 1
    const int tau  = threadIdx.x & 255;     // pipeline-local thread id
    const int c    = (blockIdx.x << 1) | pipe;
    const int p    = tau & 31;   // column group: cols 4p..4p+3
    const int h    = tau >> 5;   // i-group: i in [16h, 16h+16)

    __shared__ unsigned int EL[16384];                 // 64 KB shared by both pipes
    __shared__ float v_lds[2][KDIM];
    __shared__ __align__(16) float partial[2][8][KDIM];
    __shared__ float wsum[2][2];

    // ---- stage all 4 matrices into LDS (whole block cooperates) ----
    #pragma unroll
    for (int w = 0; w < 8; ++w) {
        const int di = ((w << 9) + threadIdx.x) << 2;
        *reinterpret_cast<uint4*>(&EL[di]) = *reinterpret_cast<const uint4*>(&Eswz[di]);
    }

    const int t_own = 1 + c * CHUNK;
    const int t_end = min(t_own + CHUNK, T_LEN);
    const int t0    = (c == 0) ? 1 : (t_own - WARM);

    // ---- init v ----
    float myv = 0.f;
    if (tau < KDIM) {
        myv = (c == 0) ? __expf(start[tau] + em[tau]) : 1.0f;
        v_lds[pipe][tau] = myv;
    }
    float r0 = myv;
    #pragma unroll
    for (int off = 32; off; off >>= 1) r0 += __shfl_down(r0, off, 64);
    if (tau < KDIM && (tau & 63) == 0) wsum[pipe][tau >> 6] = r0;
    __syncthreads();
    const float s0 = wsum[pipe][0] + wsum[pipe][1];
    float scale = 1.0f / s0;

    float g = 0.f;
    if (c == 0 && tau == 0) g = __logf(s0);

    // ---- scalar/emission prefetch for step t0 ----
    int   pm = idxArr[t0 - 1];
    float em_pref = (tau < KDIM) ? em[(size_t)t0 * KDIM + tau] : 0.f;

    const int ib = h << 4;

    for (int it = 0; it < NSTEP; ++it) {
        const int t = t0 + it;
        const bool live = (t < t_end);
        const int m = pm;
        const float d = __expf(em_pref);

        // prefetch next step's scalars + emission row (indices clamped in-bounds)
        const int tn = min(t + 1, T_LEN - 1);
        pm = idxArr[tn - 1];
        if (tau < KDIM) em_pref = em[(size_t)tn * KDIM + tau];

        // phase 1: partial matvec from LDS-resident E
        const unsigned int* Em = EL + (m << 12) + (tau << 2);
        float a0 = 0.f, a1 = 0.f, a2 = 0.f, a3 = 0.f;
        #pragma unroll
        for (int j4 = 0; j4 < 4; ++j4) {
            const uint4  pk4 = *reinterpret_cast<const uint4*>(Em + (j4 << 10));
            const float4 v4  = *reinterpret_cast<const float4*>(&v_lds[pipe][ib + (j4 << 2)]);
            float e0, e1, e2, e3;
            decode4(pk4.x, e0, e1, e2, e3);
            a0 = fmaf(v4.x, e0, a0); a1 = fmaf(v4.x, e1, a1); a2 = fmaf(v4.x, e2, a2); a3 = fmaf(v4.x, e3, a3);
            decode4(pk4.y, e0, e1, e2, e3);
            a0 = fmaf(v4.y, e0, a0); a1 = fmaf(v4.y, e1, a1); a2 = fmaf(v4.y, e2, a2); a3 = fmaf(v4.y, e3, a3);
            decode4(pk4.z, e0, e1, e2, e3);
            a0 = fmaf(v4.z, e0, a0); a1 = fmaf(v4.z, e1, a1); a2 = fmaf(v4.z, e2, a2); a3 = fmaf(v4.z, e3, a3);
            decode4(pk4.w, e0, e1, e2, e3);
            a0 = fmaf(v4.w, e0, a0); a1 = fmaf(v4.w, e1, a1); a2 = fmaf(v4.w, e2, a2); a3 = fmaf(v4.w, e3, a3);
        }
        *reinterpret_cast<float4*>(&partial[pipe][h][p << 2]) = make_float4(a0, a1, a2, a3);
        __syncthreads();

        // phase 2: combine 8 partials, apply emission + pending scale
        const bool donorm = ((t & 7) == 0) || (t == T_LEN - 1);
        float tot = 0.f;
        if (tau < KDIM) {
            tot = (partial[pipe][0][tau] + partial[pipe][1][tau] + partial[pipe][2][tau] + partial[pipe][3][tau] +
                   partial[pipe][4][tau] + partial[pipe][5][tau] + partial[pipe][6][tau] + partial[pipe][7][tau]) * (d * scale);
            if (live) v_lds[pipe][tau] = tot;
        }
        if (donorm) {
            float r = tot;
            #pragma unroll
            for (int off = 32; off; off >>= 1) r += __shfl_down(r, off, 64);
            if (tau < KDIM && (tau & 63) == 0) wsum[pipe][tau >> 6] = r;
        }
        __syncthreads();
        if (donorm) {
            const float s = wsum[pipe][0] + wsum[pipe][1];
            scale = 1.0f / s;
            if (tau == 0 && t >= t_own && t < t_end) g += __logf(s);
        } else {
            scale = 1.0f;
        }
    }

    if (tau == 0) atomicAdd(logz_acc, (double)g);
}

__global__ void finalize_kernel(const double* __restrict__ acc, float* __restrict__ out) {
    if (threadIdx.x == 0 && blockIdx.x == 0) {
        out[0] = (float)acc[0];
        out[1] = (float)acc[1];
    }
}

extern "C" void kernel_launch(void* const* d_in, const int* in_sizes, int n_in,
                              void* d_out, int out_size, void* d_ws, size_t ws_size,
                              hipStream_t stream) {
    const float* emissions = (const float*)d_in[0];
    const float* trans     = (const float*)d_in[1];
    const float* start     = (const float*)d_in[2];
    const float* cw        = (const float*)d_in[3];
    const int*   tags      = (const int*)d_in[4];
    const int*   w2w       = (const int*)d_in[5];
    const int*   icnt      = (const int*)d_in[6];
    const int*   dist      = (const int*)d_in[7];

    double*        accs   = (double*)d_ws;                         // [0]=gold, [1]=logz
    unsigned int*  Eswz   = (unsigned int*)((char*)d_ws + 64);     // 65536 B swizzled fp8
    unsigned char* idxArr = (unsigned char*)d_ws + 64 + 65536;     // T-1 bytes

    hipMemsetAsync(d_ws, 0, 16, stream);
    prep_kernel<<<512, 256, 0, stream>>>(trans, w2w, icnt, dist, Eswz, idxArr);
    gold_kernel<<<512, 256, 0, stream>>>(emissions, trans, start, cw, tags, w2w, icnt, dist, &accs[0]);
    scan_kernel<<<NCHUNK / 2, 512, 0, stream>>>(emissions, Eswz, idxArr, start, &accs[1]);
    finalize_kernel<<<1, 64, 0, stream>>>(accs, (float*)d_out);
}